// Round 4
// baseline (1140.824 us; speedup 1.0000x reference)
//
#include <hip/hip_runtime.h>

#define LRELU(v) ((v) >= 0.f ? (v) : 0.2f * (v))
#define DLRELU(v) ((v) >= 0.f ? (v) : 0.04f * (v))

constexpr int Nn = 50000;
constexpr int Ee = 800000;
constexpr int Hh = 256;
constexpr int Gg = 128;
constexpr int Oo = 10;

typedef __attribute__((ext_vector_type(8))) short short8;
typedef __attribute__((ext_vector_type(4))) float f32x4;
typedef __attribute__((ext_vector_type(4))) unsigned short us4;

__device__ inline float bf2f(unsigned short u) {
  union { unsigned int i; float f; } v; v.i = ((unsigned int)u) << 16; return v.f;
}
__device__ inline unsigned short f2bf(float f) {
  union { float f; unsigned int i; } v; v.f = f;
  unsigned int i = v.i;
  return (unsigned short)((i + 0x7FFFu + ((i >> 16) & 1u)) >> 16);
}

typedef __attribute__((address_space(1))) const unsigned int gu32;
typedef __attribute__((address_space(3))) unsigned int lu32;
__device__ inline void gload_lds16(const void* g, void* l) {
  __builtin_amdgcn_global_load_lds((gu32*)g, (lu32*)l, 16, 0, 0);
}

// ---------------------------------------------------------------------------
// CSR build
// ---------------------------------------------------------------------------
__global__ __launch_bounds__(256) void hist_kernel(
    const int* __restrict__ dst, int* __restrict__ deg)
{
  const int e = blockIdx.x * 256 + threadIdx.x;
  if (e < Ee) atomicAdd(&deg[dst[e]], 1);
}

// grid scan, 3 kernels, 1024-thread blocks
__global__ __launch_bounds__(1024) void scan1_kernel(
    const int* __restrict__ deg, int* __restrict__ bsum)
{
  const int i = blockIdx.x * 1024 + threadIdx.x;
  int v = (i < Nn) ? deg[i] : 0;
  #pragma unroll
  for (int o = 32; o; o >>= 1) v += __shfl_xor(v, o, 64);
  __shared__ int ws[16];
  const int wid = threadIdx.x >> 6, lane = threadIdx.x & 63;
  if (lane == 0) ws[wid] = v;
  __syncthreads();
  if (threadIdx.x == 0) {
    int s = 0;
    #pragma unroll
    for (int k = 0; k < 16; k++) s += ws[k];
    bsum[blockIdx.x] = s;
  }
}

__global__ __launch_bounds__(64) void scan2_kernel(
    const int* __restrict__ bsum, int* __restrict__ boff, int* __restrict__ row_ptr, int nb)
{
  if (threadIdx.x == 0) {
    int s = 0;
    for (int b = 0; b < nb; b++) { boff[b] = s; s += bsum[b]; }
    row_ptr[Nn] = s;
  }
}

__global__ __launch_bounds__(1024) void scan3_kernel(
    const int* __restrict__ deg, const int* __restrict__ boff,
    int* __restrict__ row_ptr, int* __restrict__ cursor)
{
  const int i = blockIdx.x * 1024 + threadIdx.x;
  const int wid = threadIdx.x >> 6, lane = threadIdx.x & 63;
  const int v = (i < Nn) ? deg[i] : 0;
  int inc = v;
  #pragma unroll
  for (int o = 1; o < 64; o <<= 1) {
    const int u = __shfl_up(inc, o, 64);
    if (lane >= o) inc += u;
  }
  __shared__ int ws[16];
  if (lane == 63) ws[wid] = inc;
  __syncthreads();
  if (wid == 0 && lane < 16) {
    int s = ws[lane];
    #pragma unroll
    for (int o = 1; o < 16; o <<= 1) {
      const int u = __shfl_up(s, o, 64);
      if (lane >= o) s += u;
    }
    ws[lane] = s;
  }
  __syncthreads();
  const int woff = (wid == 0) ? 0 : ws[wid - 1];
  const int excl = boff[blockIdx.x] + woff + inc - v;
  if (i < Nn) { row_ptr[i] = excl; cursor[i] = excl; }
}

__global__ __launch_bounds__(256) void fill_kernel(
    const int* __restrict__ src, const int* __restrict__ dst,
    const float* __restrict__ ea, int* __restrict__ cursor,
    int* __restrict__ csr_src, float* __restrict__ eaP)
{
  const int e = blockIdx.x * 256 + threadIdx.x;
  if (e >= Ee) return;
  const int pos = atomicAdd(&cursor[dst[e]], 1);
  csr_src[pos] = src[e];
  eaP[3 * pos + 0] = ea[3 * e + 0];
  eaP[3 * pos + 1] = ea[3 * e + 1];
  eaP[3 * pos + 2] = ea[3 * e + 2];
}

// ---------------------------------------------------------------------------
// Converters
// ---------------------------------------------------------------------------
__global__ __launch_bounds__(256) void f2bf_kernel(
    const float* __restrict__ in, unsigned short* __restrict__ out, int n4)
{
  const int i = blockIdx.x * 256 + threadIdx.x;
  if (i >= n4) return;
  const float4 v = *reinterpret_cast<const float4*>(in + (size_t)i * 4);
  us4 o; o.x = f2bf(v.x); o.y = f2bf(v.y); o.z = f2bf(v.z); o.w = f2bf(v.w);
  *reinterpret_cast<us4*>(out + (size_t)i * 4) = o;
}

// W [K,256] fp32 -> Bt [256,K] bf16 (transpose+convert)
__global__ __launch_bounds__(256) void wt_kernel(
    const float* __restrict__ W, unsigned short* __restrict__ Bt, int K)
{
  const int g = blockIdx.x * 256 + threadIdx.x;
  if (g >= 256 * K) return;
  const int c = g & 255, k = g >> 8;
  Bt[(size_t)c * K + k] = f2bf(W[(size_t)k * 256 + c]);
}

// ---------------------------------------------------------------------------
// Gather aggregation (bf16 features): S[n] = bf16( x[n] + sum_e ReLU(x[src]+ea@We+be) )
// one wave per node
// ---------------------------------------------------------------------------
template<int DIN>
__global__ __launch_bounds__(256) void agg_gather(
    const unsigned short* __restrict__ x, const float* __restrict__ eaP,
    const float* __restrict__ We, const float* __restrict__ be,
    const int* __restrict__ row_ptr, const int* __restrict__ csr_src,
    unsigned short* __restrict__ S)
{
  constexpr int FPL = DIN / 64;
  const int wv   = threadIdx.x >> 6;
  const int lane = threadIdx.x & 63;
  const int n = blockIdx.x * 4 + wv;
  if (n >= Nn) return;
  const int fo = lane * FPL;

  float w0[FPL], w1[FPL], w2[FPL], bb[FPL], acc[FPL];
  #pragma unroll
  for (int j = 0; j < FPL; j++) {
    w0[j] = We[0 * DIN + fo + j];
    w1[j] = We[1 * DIN + fo + j];
    w2[j] = We[2 * DIN + fo + j];
    bb[j] = be[fo + j];
    acc[j] = 0.f;
  }

  const int beg = row_ptr[n], end = row_ptr[n + 1];
  for (int i = beg; i < end; i++) {
    const int s = csr_src[i];
    const float a0 = eaP[3 * i + 0], a1 = eaP[3 * i + 1], a2 = eaP[3 * i + 2];
    float xv[FPL];
    if constexpr (FPL == 4) {
      const us4 v = *reinterpret_cast<const us4*>(x + (size_t)s * DIN + fo);
      xv[0] = bf2f(v.x); xv[1] = bf2f(v.y); xv[2] = bf2f(v.z); xv[3] = bf2f(v.w);
    } else {
      const unsigned int u = *reinterpret_cast<const unsigned int*>(x + (size_t)s * DIN + fo);
      xv[0] = bf2f((unsigned short)(u & 0xFFFF));
      xv[1] = bf2f((unsigned short)(u >> 16));
    }
    #pragma unroll
    for (int j = 0; j < FPL; j++) {
      const float m = xv[j] + a0 * w0[j] + a1 * w1[j] + a2 * w2[j] + bb[j];
      acc[j] += fmaxf(m, 0.f);
    }
  }

  unsigned short o[FPL];
  if constexpr (FPL == 4) {
    const us4 v = *reinterpret_cast<const us4*>(x + (size_t)n * DIN + fo);
    o[0] = f2bf(bf2f(v.x) + acc[0]); o[1] = f2bf(bf2f(v.y) + acc[1]);
    o[2] = f2bf(bf2f(v.z) + acc[2]); o[3] = f2bf(bf2f(v.w) + acc[3]);
    us4 ov; ov.x = o[0]; ov.y = o[1]; ov.z = o[2]; ov.w = o[3];
    *reinterpret_cast<us4*>(S + (size_t)n * DIN + fo) = ov;
  } else {
    const unsigned int u = *reinterpret_cast<const unsigned int*>(x + (size_t)n * DIN + fo);
    o[0] = f2bf(bf2f((unsigned short)(u & 0xFFFF)) + acc[0]);
    o[1] = f2bf(bf2f((unsigned short)(u >> 16)) + acc[1]);
    *reinterpret_cast<unsigned int*>(S + (size_t)n * DIN + fo) =
        (unsigned int)o[0] | ((unsigned int)o[1] << 16);
  }
}

// ---------------------------------------------------------------------------
// MFMA GEMM (m97-style): C[N,256] = epi( A[N,K]bf16 @ W[K,256] ), Bt=W^T [256][K]
// 128x128 block tile, 4 waves (2x2, 64x64 each), BK=64
// A,B staged via global_load_lds (linear dest) with XOR(row&7) swizzle:
// global source pre-swizzled, ds_read applies same XOR -> 2-way conflicts (free)
// ---------------------------------------------------------------------------
template<int K, bool DOBN>
__global__ __launch_bounds__(256) void gemm_mfma(
    const unsigned short* __restrict__ A, const unsigned short* __restrict__ Bt,
    const float* __restrict__ bias,
    const float* __restrict__ gamma, const float* __restrict__ beta,
    const float* __restrict__ mu, const float* __restrict__ var,
    unsigned short* __restrict__ C)
{
  __shared__ __align__(16) unsigned short lA[128 * 64];  // 16 KB
  __shared__ __align__(16) unsigned short lB[128 * 64];  // 16 KB
  const int t = threadIdx.x;
  const int lane = t & 63, wid = t >> 6;
  const int wrow = wid >> 1, wcol = wid & 1;
  const int l15 = lane & 15, hi = lane >> 4;
  const int n0 = blockIdx.y * 128;
  const int c0 = blockIdx.x * 128;
  const int srow = lane >> 3;    // staging: row within chunk
  const int sslot = lane & 7;    // staging: 16B slot

  f32x4 acc[4][4] = {};

  for (int k0 = 0; k0 < K; k0 += 64) {
    #pragma unroll
    for (int c = 0; c < 4; c++) {
      const int chunk = wid * 4 + c;              // 0..15
      const int row = chunk * 8 + srow;           // 0..127
      const int scol = (sslot ^ (row & 7)) * 8;   // pre-swizzled source slot
      const int gr = min(n0 + row, Nn - 1);
      gload_lds16(A + (size_t)gr * K + k0 + scol, (char*)lA + chunk * 1024);
      const int cb = c0 + row;                    // < 256 always
      gload_lds16(Bt + (size_t)cb * K + k0 + scol, (char*)lB + chunk * 1024);
    }
    __syncthreads();
    #pragma unroll
    for (int kk = 0; kk < 2; kk++) {
      short8 av[4], bv[4];
      #pragma unroll
      for (int rf = 0; rf < 4; rf++) {
        const int ar = wrow * 64 + rf * 16 + l15;
        av[rf] = *reinterpret_cast<const short8*>(
            (const char*)lA + ar * 128 + (((kk * 4 + hi) ^ (ar & 7)) << 4));
      }
      #pragma unroll
      for (int cf = 0; cf < 4; cf++) {
        const int br = wcol * 64 + cf * 16 + l15;
        bv[cf] = *reinterpret_cast<const short8*>(
            (const char*)lB + br * 128 + (((kk * 4 + hi) ^ (br & 7)) << 4));
      }
      #pragma unroll
      for (int rf = 0; rf < 4; rf++)
        #pragma unroll
        for (int cf = 0; cf < 4; cf++)
          acc[rf][cf] = __builtin_amdgcn_mfma_f32_16x16x32_bf16(av[rf], bv[cf], acc[rf][cf], 0, 0, 0);
    }
    __syncthreads();
  }

  #pragma unroll
  for (int cf = 0; cf < 4; cf++) {
    const int col = c0 + wcol * 64 + cf * 16 + l15;
    const float bs = bias[col];
    float gm = 0.f, bt2 = 0.f, mm = 0.f, iv = 0.f;
    if constexpr (DOBN) {
      gm = gamma[col]; bt2 = beta[col]; mm = mu[col];
      iv = rsqrtf(var[col] + 1e-5f);
    }
    #pragma unroll
    for (int rf = 0; rf < 4; rf++) {
      #pragma unroll
      for (int rg = 0; rg < 4; rg++) {
        const int row = n0 + wrow * 64 + rf * 16 + hi * 4 + rg;
        if (row >= Nn) continue;
        float v = acc[rf][cf][rg] + bs;
        if constexpr (DOBN) v = gm * (v - mm) * iv + bt2;
        v = LRELU(v);
        C[(size_t)row * 256 + col] = f2bf(v);
      }
    }
  }
}

// ---------------------------------------------------------------------------
// Pool: segment_sum (sorted batch) of bf16 features into pooled[G,768] fp32
// ---------------------------------------------------------------------------
__global__ __launch_bounds__(256) void pool_kernel(
    const unsigned short* __restrict__ xl, const int* __restrict__ batch,
    float* __restrict__ pooled, int layer)
{
  constexpr int NPB = 16;
  const int n0 = blockIdx.x * NPB;
  const int c  = threadIdx.x;
  if (n0 >= Nn) return;
  float acc = 0.f;
  int curb = batch[n0];
  for (int i = 0; i < NPB; i++) {
    const int n = n0 + i;
    if (n >= Nn) break;
    const int b = batch[n];
    if (b != curb) {
      atomicAdd(pooled + (size_t)curb * 768 + layer * 256 + c, acc);
      acc = 0.f;
      curb = b;
    }
    acc += bf2f(xl[(size_t)n * 256 + c]);
  }
  atomicAdd(pooled + (size_t)curb * 768 + layer * 256 + c, acc);
}

// ---------------------------------------------------------------------------
// Head GEMM: out[G,M] = act( in[G,K] @ W[K,M] + b ), fp32
// block: 32 graphs x 64 cols; thread: 8 rows x 1 col (8 independent chains)
// ---------------------------------------------------------------------------
template<int K, int M, bool ACT>
__global__ __launch_bounds__(256) void head_gemm(
    const float* __restrict__ in, const float* __restrict__ W,
    const float* __restrict__ b, float* __restrict__ out)
{
  constexpr int BK = 32;
  __shared__ float lin[32][BK];
  const int t = threadIdx.x;
  const int c = blockIdx.x * 64 + (t & 63);
  const int rg = t >> 6;              // 0..3 -> rows rg*8..rg*8+7
  const int r0 = blockIdx.y * 32;
  const int srow = t >> 3;            // staging row 0..31
  const int sk = (t & 7) * 4;         // staging k offset

  float acc[8] = {};
  for (int k0 = 0; k0 < K; k0 += BK) {
    if (k0 + sk < K) {
      const float4 v = *reinterpret_cast<const float4*>(in + (size_t)(r0 + srow) * K + k0 + sk);
      *reinterpret_cast<float4*>(&lin[srow][sk]) = v;
    }
    __syncthreads();
    const int kmax = (K - k0 < BK) ? (K - k0) : BK;
    for (int kk = 0; kk < kmax; kk++) {
      const float w = (c < M) ? W[(size_t)(k0 + kk) * M + c] : 0.f;
      #pragma unroll
      for (int i = 0; i < 8; i++)
        acc[i] = fmaf(lin[rg * 8 + i][kk], w, acc[i]);
    }
    __syncthreads();
  }
  if (c < M) {
    const float bs = b[c];
    #pragma unroll
    for (int i = 0; i < 8; i++) {
      float v = acc[i] + bs;
      if (ACT) v = DLRELU(v);
      out[(size_t)(r0 + rg * 8 + i) * M + c] = v;
    }
  }
}

// ---------------------------------------------------------------------------
extern "C" void kernel_launch(void* const* d_in, const int* in_sizes, int n_in,
                              void* d_out, int out_size, void* d_ws, size_t ws_size,
                              hipStream_t stream)
{
  const float* x     = (const float*)d_in[0];
  const int*   ei    = (const int*)d_in[1];
  const float* ea    = (const float*)d_in[2];
  const int*   batch = (const int*)d_in[3];
  const int* src = ei;
  const int* dst = ei + Ee;

  const float *We[3], *be_[3], *W1[3], *b1[3], *g_[3], *bt_[3], *mu_[3], *var_[3], *W2[3], *b2[3];
  for (int l = 0; l < 3; l++) {
    const int base = 4 + l * 10;
    We[l]  = (const float*)d_in[base + 0];
    be_[l] = (const float*)d_in[base + 1];
    W1[l]  = (const float*)d_in[base + 2];
    b1[l]  = (const float*)d_in[base + 3];
    g_[l]  = (const float*)d_in[base + 4];
    bt_[l] = (const float*)d_in[base + 5];
    mu_[l] = (const float*)d_in[base + 6];
    var_[l]= (const float*)d_in[base + 7];
    W2[l]  = (const float*)d_in[base + 8];
    b2[l]  = (const float*)d_in[base + 9];
  }
  const float *Wm[4], *bm[4];
  for (int i = 0; i < 4; i++) {
    Wm[i] = (const float*)d_in[34 + 2 * i];
    bm[i] = (const float*)d_in[35 + 2 * i];
  }

  // ---- workspace layout ----
  int* deg     = (int*)d_ws;                        // Nn
  int* cursor  = deg + Nn;                          // Nn
  int* row_ptr = cursor + Nn;                       // Nn+4
  int* bsum    = row_ptr + Nn + 4;                  // 64
  int* boff    = bsum + 64;                         // 64
  int* csr_src = boff + 64;                         // Ee
  float* eaP   = (float*)(csr_src + Ee);            // 3*Ee
  unsigned short* x0bf = (unsigned short*)(eaP + (size_t)3 * Ee);  // Nn*128
  unsigned short* Wt11 = x0bf + (size_t)Nn * 128;   // 256x128
  unsigned short* Wt12 = Wt11 + 32768;              // 256x256 each
  unsigned short* Wt21 = Wt12 + 65536;
  unsigned short* Wt22 = Wt21 + 65536;
  unsigned short* Wt31 = Wt22 + 65536;
  unsigned short* Wt32 = Wt31 + 65536;
  unsigned short* S    = Wt32 + 65536;              // Nn*256
  unsigned short* Y    = S  + (size_t)Nn * Hh;      // Nn*256
  unsigned short* XB0  = Y  + (size_t)Nn * Hh;      // Nn*256
  unsigned short* XB1  = XB0 + (size_t)Nn * Hh;     // Nn*256
  float* pooled = (float*)(XB1 + (size_t)Nn * Hh);  // Gg*768
  float* h1    = pooled + (size_t)Gg * 768;         // Gg*200
  float* h2    = h1 + (size_t)Gg * 200;             // Gg*200
  float* outf  = (float*)d_out;

  const dim3 gemmGrid(2, (Nn + 127) / 128);
  const int  poolGrid = (Nn + 15) / 16;
  const int  aggGrid  = (Nn + 3) / 4;
  const int  eGrid    = (Ee + 255) / 256;
  const int  sGrid    = (Nn + 1023) / 1024;

  hipMemsetAsync(deg, 0, Nn * sizeof(int), stream);
  hipMemsetAsync(pooled, 0, (size_t)Gg * 768 * sizeof(float), stream);

  // CSR build (once)
  hist_kernel<<<eGrid, 256, 0, stream>>>(dst, deg);
  scan1_kernel<<<sGrid, 1024, 0, stream>>>(deg, bsum);
  scan2_kernel<<<1, 64, 0, stream>>>(bsum, boff, row_ptr, sGrid);
  scan3_kernel<<<sGrid, 1024, 0, stream>>>(deg, boff, row_ptr, cursor);
  fill_kernel<<<eGrid, 256, 0, stream>>>(src, dst, ea, cursor, csr_src, eaP);

  // converts
  f2bf_kernel<<<(Nn * 128 / 4 + 255) / 256, 256, 0, stream>>>(x, x0bf, Nn * 128 / 4);
  wt_kernel<<<(256 * 128 + 255) / 256, 256, 0, stream>>>(W1[0], Wt11, 128);
  wt_kernel<<<(256 * 256 + 255) / 256, 256, 0, stream>>>(W2[0], Wt12, 256);
  wt_kernel<<<(256 * 256 + 255) / 256, 256, 0, stream>>>(W1[1], Wt21, 256);
  wt_kernel<<<(256 * 256 + 255) / 256, 256, 0, stream>>>(W2[1], Wt22, 256);
  wt_kernel<<<(256 * 256 + 255) / 256, 256, 0, stream>>>(W1[2], Wt31, 256);
  wt_kernel<<<(256 * 256 + 255) / 256, 256, 0, stream>>>(W2[2], Wt32, 256);

  // ---- layer 1 (din = 128) ----
  agg_gather<128><<<aggGrid, 256, 0, stream>>>(x0bf, eaP, We[0], be_[0], row_ptr, csr_src, S);
  gemm_mfma<128, true><<<gemmGrid, 256, 0, stream>>>(
      S, Wt11, b1[0], g_[0], bt_[0], mu_[0], var_[0], Y);
  gemm_mfma<256, false><<<gemmGrid, 256, 0, stream>>>(
      Y, Wt12, b2[0], nullptr, nullptr, nullptr, nullptr, XB0);
  pool_kernel<<<poolGrid, 256, 0, stream>>>(XB0, batch, pooled, 0);

  // ---- layer 2 (din = 256) ----
  agg_gather<256><<<aggGrid, 256, 0, stream>>>(XB0, eaP, We[1], be_[1], row_ptr, csr_src, S);
  gemm_mfma<256, true><<<gemmGrid, 256, 0, stream>>>(
      S, Wt21, b1[1], g_[1], bt_[1], mu_[1], var_[1], Y);
  gemm_mfma<256, false><<<gemmGrid, 256, 0, stream>>>(
      Y, Wt22, b2[1], nullptr, nullptr, nullptr, nullptr, XB1);
  pool_kernel<<<poolGrid, 256, 0, stream>>>(XB1, batch, pooled, 1);

  // ---- layer 3 (din = 256) ----
  agg_gather<256><<<aggGrid, 256, 0, stream>>>(XB1, eaP, We[2], be_[2], row_ptr, csr_src, S);
  gemm_mfma<256, true><<<gemmGrid, 256, 0, stream>>>(
      S, Wt31, b1[2], g_[2], bt_[2], mu_[2], var_[2], Y);
  gemm_mfma<256, false><<<gemmGrid, 256, 0, stream>>>(
      Y, Wt32, b2[2], nullptr, nullptr, nullptr, nullptr, XB0);
  pool_kernel<<<poolGrid, 256, 0, stream>>>(XB0, batch, pooled, 2);

  // ---- MLP head (tiled fp32 GEMMs) ----
  head_gemm<768, 200, true><<<dim3(4, 4), 256, 0, stream>>>(pooled, Wm[0], bm[0], h1);
  head_gemm<200, 200, true><<<dim3(4, 4), 256, 0, stream>>>(h1, Wm[1], bm[1], h2);
  head_gemm<200, 200, true><<<dim3(4, 4), 256, 0, stream>>>(h2, Wm[2], bm[2], h1);
  head_gemm<200, 10, false><<<dim3(1, 4), 256, 0, stream>>>(h1, Wm[3], bm[3], outf);
}

// Round 5
// 728.694 us; speedup vs baseline: 1.5656x; 1.5656x over previous
//
#include <hip/hip_runtime.h>

#define LRELU(v) ((v) >= 0.f ? (v) : 0.2f * (v))
#define DLRELU(v) ((v) >= 0.f ? (v) : 0.04f * (v))

constexpr int Nn = 50000;
constexpr int Ee = 800000;
constexpr int Hh = 256;
constexpr int Gg = 128;
constexpr int Oo = 10;

typedef __attribute__((ext_vector_type(8))) short short8;
typedef __attribute__((ext_vector_type(4))) float f32x4;
typedef __attribute__((ext_vector_type(4))) unsigned short us4;

__device__ inline float bf2f(unsigned short u) {
  union { unsigned int i; float f; } v; v.i = ((unsigned int)u) << 16; return v.f;
}
__device__ inline unsigned short f2bf(float f) {
  union { float f; unsigned int i; } v; v.f = f;
  unsigned int i = v.i;
  return (unsigned short)((i + 0x7FFFu + ((i >> 16) & 1u)) >> 16);
}

typedef __attribute__((address_space(1))) const unsigned int gu32;
typedef __attribute__((address_space(3))) unsigned int lu32;
__device__ inline void gload_lds16(const void* g, void* l) {
  __builtin_amdgcn_global_load_lds((gu32*)g, (lu32*)l, 16, 0, 0);
}

// ---------------------------------------------------------------------------
// CSR build
// ---------------------------------------------------------------------------
__global__ __launch_bounds__(256) void hist_kernel(
    const int* __restrict__ dst, int* __restrict__ deg)
{
  const int e = blockIdx.x * 256 + threadIdx.x;
  if (e < Ee) atomicAdd(&deg[dst[e]], 1);
}

__global__ __launch_bounds__(1024) void scan1_kernel(
    const int* __restrict__ deg, int* __restrict__ bsum)
{
  const int i = blockIdx.x * 1024 + threadIdx.x;
  int v = (i < Nn) ? deg[i] : 0;
  #pragma unroll
  for (int o = 32; o; o >>= 1) v += __shfl_xor(v, o, 64);
  __shared__ int ws[16];
  const int wid = threadIdx.x >> 6, lane = threadIdx.x & 63;
  if (lane == 0) ws[wid] = v;
  __syncthreads();
  if (threadIdx.x == 0) {
    int s = 0;
    #pragma unroll
    for (int k = 0; k < 16; k++) s += ws[k];
    bsum[blockIdx.x] = s;
  }
}

__global__ __launch_bounds__(64) void scan2_kernel(
    const int* __restrict__ bsum, int* __restrict__ boff, int* __restrict__ row_ptr, int nb)
{
  if (threadIdx.x == 0) {
    int s = 0;
    for (int b = 0; b < nb; b++) { boff[b] = s; s += bsum[b]; }
    row_ptr[Nn] = s;
  }
}

__global__ __launch_bounds__(1024) void scan3_kernel(
    const int* __restrict__ deg, const int* __restrict__ boff,
    int* __restrict__ row_ptr, int* __restrict__ cursor)
{
  const int i = blockIdx.x * 1024 + threadIdx.x;
  const int wid = threadIdx.x >> 6, lane = threadIdx.x & 63;
  const int v = (i < Nn) ? deg[i] : 0;
  int inc = v;
  #pragma unroll
  for (int o = 1; o < 64; o <<= 1) {
    const int u = __shfl_up(inc, o, 64);
    if (lane >= o) inc += u;
  }
  __shared__ int ws[16];
  if (lane == 63) ws[wid] = inc;
  __syncthreads();
  if (wid == 0 && lane < 16) {
    int s = ws[lane];
    #pragma unroll
    for (int o = 1; o < 16; o <<= 1) {
      const int u = __shfl_up(s, o, 64);
      if (lane >= o) s += u;
    }
    ws[lane] = s;
  }
  __syncthreads();
  const int woff = (wid == 0) ? 0 : ws[wid - 1];
  const int excl = boff[blockIdx.x] + woff + inc - v;
  if (i < Nn) { row_ptr[i] = excl; cursor[i] = excl; }
}

__global__ __launch_bounds__(256) void fill_kernel(
    const int* __restrict__ src, const int* __restrict__ dst,
    const float* __restrict__ ea, int* __restrict__ cursor,
    int* __restrict__ csr_src, float* __restrict__ eaP)
{
  const int e = blockIdx.x * 256 + threadIdx.x;
  if (e >= Ee) return;
  const int pos = atomicAdd(&cursor[dst[e]], 1);
  csr_src[pos] = src[e];
  eaP[3 * pos + 0] = ea[3 * e + 0];
  eaP[3 * pos + 1] = ea[3 * e + 1];
  eaP[3 * pos + 2] = ea[3 * e + 2];
}

// ---------------------------------------------------------------------------
// Converters
// ---------------------------------------------------------------------------
__global__ __launch_bounds__(256) void f2bf_kernel(
    const float* __restrict__ in, unsigned short* __restrict__ out, int n4)
{
  const int i = blockIdx.x * 256 + threadIdx.x;
  if (i >= n4) return;
  const float4 v = *reinterpret_cast<const float4*>(in + (size_t)i * 4);
  us4 o; o.x = f2bf(v.x); o.y = f2bf(v.y); o.z = f2bf(v.z); o.w = f2bf(v.w);
  *reinterpret_cast<us4*>(out + (size_t)i * 4) = o;
}

// W [K,256] fp32 -> Bt [256,K] bf16 (transpose+convert)
__global__ __launch_bounds__(256) void wt_kernel(
    const float* __restrict__ W, unsigned short* __restrict__ Bt, int K)
{
  const int g = blockIdx.x * 256 + threadIdx.x;
  if (g >= 256 * K) return;
  const int c = g & 255, k = g >> 8;
  Bt[(size_t)c * K + k] = f2bf(W[(size_t)k * 256 + c]);
}

// head weights: W[K,M] fp32 -> Bt[256,Kpad] bf16 transposed, zero-padded
__global__ __launch_bounds__(256) void headwt_kernel(
    const float* __restrict__ W, unsigned short* __restrict__ Bt,
    int K, int M, int Kpad)
{
  const int g = blockIdx.x * 256 + threadIdx.x;
  if (g >= 256 * Kpad) return;
  const int c = g / Kpad, k = g % Kpad;
  Bt[(size_t)c * Kpad + k] = (c < M && k < K) ? f2bf(W[(size_t)k * M + c]) : (unsigned short)0;
}

// ---------------------------------------------------------------------------
// Gather aggregation (bf16 features): S[n] = bf16( x[n] + sum_e ReLU(x[src]+ea@We+be) )
// ---------------------------------------------------------------------------
template<int DIN>
__global__ __launch_bounds__(256) void agg_gather(
    const unsigned short* __restrict__ x, const float* __restrict__ eaP,
    const float* __restrict__ We, const float* __restrict__ be,
    const int* __restrict__ row_ptr, const int* __restrict__ csr_src,
    unsigned short* __restrict__ S)
{
  constexpr int FPL = DIN / 64;
  const int wv   = threadIdx.x >> 6;
  const int lane = threadIdx.x & 63;
  const int n = blockIdx.x * 4 + wv;
  if (n >= Nn) return;
  const int fo = lane * FPL;

  float w0[FPL], w1[FPL], w2[FPL], bb[FPL], acc[FPL];
  #pragma unroll
  for (int j = 0; j < FPL; j++) {
    w0[j] = We[0 * DIN + fo + j];
    w1[j] = We[1 * DIN + fo + j];
    w2[j] = We[2 * DIN + fo + j];
    bb[j] = be[fo + j];
    acc[j] = 0.f;
  }

  const int beg = row_ptr[n], end = row_ptr[n + 1];
  for (int i = beg; i < end; i++) {
    const int s = csr_src[i];
    const float a0 = eaP[3 * i + 0], a1 = eaP[3 * i + 1], a2 = eaP[3 * i + 2];
    float xv[FPL];
    if constexpr (FPL == 4) {
      const us4 v = *reinterpret_cast<const us4*>(x + (size_t)s * DIN + fo);
      xv[0] = bf2f(v.x); xv[1] = bf2f(v.y); xv[2] = bf2f(v.z); xv[3] = bf2f(v.w);
    } else {
      const unsigned int u = *reinterpret_cast<const unsigned int*>(x + (size_t)s * DIN + fo);
      xv[0] = bf2f((unsigned short)(u & 0xFFFF));
      xv[1] = bf2f((unsigned short)(u >> 16));
    }
    #pragma unroll
    for (int j = 0; j < FPL; j++) {
      const float m = xv[j] + a0 * w0[j] + a1 * w1[j] + a2 * w2[j] + bb[j];
      acc[j] += fmaxf(m, 0.f);
    }
  }

  unsigned short o[FPL];
  if constexpr (FPL == 4) {
    const us4 v = *reinterpret_cast<const us4*>(x + (size_t)n * DIN + fo);
    o[0] = f2bf(bf2f(v.x) + acc[0]); o[1] = f2bf(bf2f(v.y) + acc[1]);
    o[2] = f2bf(bf2f(v.z) + acc[2]); o[3] = f2bf(bf2f(v.w) + acc[3]);
    us4 ov; ov.x = o[0]; ov.y = o[1]; ov.z = o[2]; ov.w = o[3];
    *reinterpret_cast<us4*>(S + (size_t)n * DIN + fo) = ov;
  } else {
    const unsigned int u = *reinterpret_cast<const unsigned int*>(x + (size_t)n * DIN + fo);
    o[0] = f2bf(bf2f((unsigned short)(u & 0xFFFF)) + acc[0]);
    o[1] = f2bf(bf2f((unsigned short)(u >> 16)) + acc[1]);
    *reinterpret_cast<unsigned int*>(S + (size_t)n * DIN + fo) =
        (unsigned int)o[0] | ((unsigned int)o[1] << 16);
  }
}

// ---------------------------------------------------------------------------
// MFMA GEMM (m97-style): C[N,256] = epi( A[N,K]bf16 @ W[K,256] ), Bt=W^T [256][K]
// 128x128 block tile, 4 waves (2x2, 64x64 each), BK=64, gload_lds + XOR swizzle
// ---------------------------------------------------------------------------
template<int K, bool DOBN>
__global__ __launch_bounds__(256) void gemm_mfma(
    const unsigned short* __restrict__ A, const unsigned short* __restrict__ Bt,
    const float* __restrict__ bias,
    const float* __restrict__ gamma, const float* __restrict__ beta,
    const float* __restrict__ mu, const float* __restrict__ var,
    unsigned short* __restrict__ C)
{
  __shared__ __align__(16) unsigned short lA[128 * 64];
  __shared__ __align__(16) unsigned short lB[128 * 64];
  const int t = threadIdx.x;
  const int lane = t & 63, wid = t >> 6;
  const int wrow = wid >> 1, wcol = wid & 1;
  const int l15 = lane & 15, hi = lane >> 4;
  const int n0 = blockIdx.y * 128;
  const int c0 = blockIdx.x * 128;
  const int srow = lane >> 3;
  const int sslot = lane & 7;

  f32x4 acc[4][4] = {};

  for (int k0 = 0; k0 < K; k0 += 64) {
    #pragma unroll
    for (int c = 0; c < 4; c++) {
      const int chunk = wid * 4 + c;
      const int row = chunk * 8 + srow;
      const int scol = (sslot ^ (row & 7)) * 8;
      const int gr = min(n0 + row, Nn - 1);
      gload_lds16(A + (size_t)gr * K + k0 + scol, (char*)lA + chunk * 1024);
      const int cb = c0 + row;
      gload_lds16(Bt + (size_t)cb * K + k0 + scol, (char*)lB + chunk * 1024);
    }
    __syncthreads();
    #pragma unroll
    for (int kk = 0; kk < 2; kk++) {
      short8 av[4], bv[4];
      #pragma unroll
      for (int rf = 0; rf < 4; rf++) {
        const int ar = wrow * 64 + rf * 16 + l15;
        av[rf] = *reinterpret_cast<const short8*>(
            (const char*)lA + ar * 128 + (((kk * 4 + hi) ^ (ar & 7)) << 4));
      }
      #pragma unroll
      for (int cf = 0; cf < 4; cf++) {
        const int br = wcol * 64 + cf * 16 + l15;
        bv[cf] = *reinterpret_cast<const short8*>(
            (const char*)lB + br * 128 + (((kk * 4 + hi) ^ (br & 7)) << 4));
      }
      #pragma unroll
      for (int rf = 0; rf < 4; rf++)
        #pragma unroll
        for (int cf = 0; cf < 4; cf++)
          acc[rf][cf] = __builtin_amdgcn_mfma_f32_16x16x32_bf16(av[rf], bv[cf], acc[rf][cf], 0, 0, 0);
    }
    __syncthreads();
  }

  #pragma unroll
  for (int cf = 0; cf < 4; cf++) {
    const int col = c0 + wcol * 64 + cf * 16 + l15;
    const float bs = bias[col];
    float gm = 0.f, bt2 = 0.f, mm = 0.f, iv = 0.f;
    if constexpr (DOBN) {
      gm = gamma[col]; bt2 = beta[col]; mm = mu[col];
      iv = rsqrtf(var[col] + 1e-5f);
    }
    #pragma unroll
    for (int rf = 0; rf < 4; rf++) {
      #pragma unroll
      for (int rg = 0; rg < 4; rg++) {
        const int row = n0 + wrow * 64 + rf * 16 + hi * 4 + rg;
        if (row >= Nn) continue;
        float v = acc[rf][cf][rg] + bs;
        if constexpr (DOBN) v = gm * (v - mm) * iv + bt2;
        v = LRELU(v);
        C[(size_t)row * 256 + col] = f2bf(v);
      }
    }
  }
}

// ---------------------------------------------------------------------------
// Pool: segment_sum (sorted batch) of bf16 features into pooled[G,768] fp32
// ---------------------------------------------------------------------------
__global__ __launch_bounds__(256) void pool_kernel(
    const unsigned short* __restrict__ xl, const int* __restrict__ batch,
    float* __restrict__ pooled, int layer)
{
  constexpr int NPB = 16;
  const int n0 = blockIdx.x * NPB;
  const int c  = threadIdx.x;
  if (n0 >= Nn) return;
  float acc = 0.f;
  int curb = batch[n0];
  for (int i = 0; i < NPB; i++) {
    const int n = n0 + i;
    if (n >= Nn) break;
    const int b = batch[n];
    if (b != curb) {
      atomicAdd(pooled + (size_t)curb * 768 + layer * 256 + c, acc);
      acc = 0.f;
      curb = b;
    }
    acc += bf2f(xl[(size_t)n * 256 + c]);
  }
  atomicAdd(pooled + (size_t)curb * 768 + layer * 256 + c, acc);
}

// ---------------------------------------------------------------------------
// Fused MFMA head: 4 blocks x 32 graphs, all 4 layers, act in swizzled LDS
// ---------------------------------------------------------------------------
__global__ __launch_bounds__(256) void head_fused(
    const unsigned short* __restrict__ P,   // [128][768] bf16
    const unsigned short* __restrict__ B1t, // [256][768] bf16 (zero-padded)
    const unsigned short* __restrict__ B2t, // [256][256]
    const unsigned short* __restrict__ B3t, // [256][256]
    const unsigned short* __restrict__ B4t, // [256][256] (rows 0..9 real)
    const float* __restrict__ b1, const float* __restrict__ b2,
    const float* __restrict__ b3, const float* __restrict__ b4,
    float* __restrict__ out)                // [128][10]
{
  __shared__ __align__(16) unsigned short act[32 * 256];  // 16 KB, swizzled
  const int t = threadIdx.x, lane = t & 63, wid = t >> 6;
  const int l15 = lane & 15, hi = lane >> 4;
  const int r0 = blockIdx.x * 32;

  f32x4 acc[2][4];

  // ---------- layer 1: P[32][768] @ B1 -> act ----------
  #pragma unroll
  for (int rf = 0; rf < 2; rf++)
    #pragma unroll
    for (int cf = 0; cf < 4; cf++) acc[rf][cf] = (f32x4){0.f, 0.f, 0.f, 0.f};
  #pragma unroll 2
  for (int ks = 0; ks < 24; ks++) {
    short8 bv[4], av[2];
    #pragma unroll
    for (int cf = 0; cf < 4; cf++) {
      const int c = wid * 64 + cf * 16 + l15;
      bv[cf] = *reinterpret_cast<const short8*>(B1t + (size_t)c * 768 + ks * 32 + hi * 8);
    }
    #pragma unroll
    for (int rf = 0; rf < 2; rf++)
      av[rf] = *reinterpret_cast<const short8*>(
          P + (size_t)(r0 + rf * 16 + l15) * 768 + ks * 32 + hi * 8);
    #pragma unroll
    for (int rf = 0; rf < 2; rf++)
      #pragma unroll
      for (int cf = 0; cf < 4; cf++)
        acc[rf][cf] = __builtin_amdgcn_mfma_f32_16x16x32_bf16(av[rf], bv[cf], acc[rf][cf], 0, 0, 0);
  }
  #pragma unroll
  for (int cf = 0; cf < 4; cf++) {
    const int c = wid * 64 + cf * 16 + l15;
    const float bs = (c < 200) ? b1[c] : 0.f;
    const int slot0 = c >> 3;
    #pragma unroll
    for (int rf = 0; rf < 2; rf++)
      #pragma unroll
      for (int rg = 0; rg < 4; rg++) {
        const int row = rf * 16 + hi * 4 + rg;
        const float v = DLRELU(acc[rf][cf][rg] + bs);
        act[row * 256 + ((slot0 ^ (row & 7)) << 3) + (c & 7)] = f2bf(v);
      }
  }
  __syncthreads();

  // ---------- layers 2 & 3: act @ B -> act ----------
  #pragma unroll
  for (int L = 0; L < 2; L++) {
    const unsigned short* B = (L == 0) ? B2t : B3t;
    const float* bias = (L == 0) ? b2 : b3;
    #pragma unroll
    for (int rf = 0; rf < 2; rf++)
      #pragma unroll
      for (int cf = 0; cf < 4; cf++) acc[rf][cf] = (f32x4){0.f, 0.f, 0.f, 0.f};
    #pragma unroll
    for (int ks = 0; ks < 8; ks++) {
      short8 bv[4], av[2];
      #pragma unroll
      for (int cf = 0; cf < 4; cf++) {
        const int c = wid * 64 + cf * 16 + l15;
        bv[cf] = *reinterpret_cast<const short8*>(B + (size_t)c * 256 + ks * 32 + hi * 8);
      }
      #pragma unroll
      for (int rf = 0; rf < 2; rf++) {
        const int row = rf * 16 + l15;
        const int slot = ks * 4 + hi;
        av[rf] = *reinterpret_cast<const short8*>(
            act + row * 256 + ((slot ^ (row & 7)) << 3));
      }
      #pragma unroll
      for (int rf = 0; rf < 2; rf++)
        #pragma unroll
        for (int cf = 0; cf < 4; cf++)
          acc[rf][cf] = __builtin_amdgcn_mfma_f32_16x16x32_bf16(av[rf], bv[cf], acc[rf][cf], 0, 0, 0);
    }
    __syncthreads();  // all act reads done before overwrite
    #pragma unroll
    for (int cf = 0; cf < 4; cf++) {
      const int c = wid * 64 + cf * 16 + l15;
      const float bs = (c < 200) ? bias[c] : 0.f;
      const int slot0 = c >> 3;
      #pragma unroll
      for (int rf = 0; rf < 2; rf++)
        #pragma unroll
        for (int rg = 0; rg < 4; rg++) {
          const int row = rf * 16 + hi * 4 + rg;
          const float v = DLRELU(acc[rf][cf][rg] + bs);
          act[row * 256 + ((slot0 ^ (row & 7)) << 3) + (c & 7)] = f2bf(v);
        }
    }
    __syncthreads();
  }

  // ---------- layer 4: act @ B4 -> out (wave 0 only, cols 0..9) ----------
  if (wid == 0) {
    f32x4 a4[2] = {};
    #pragma unroll
    for (int ks = 0; ks < 8; ks++) {
      short8 av[2];
      const short8 bv = *reinterpret_cast<const short8*>(
          B4t + (size_t)l15 * 256 + ks * 32 + hi * 8);
      #pragma unroll
      for (int rf = 0; rf < 2; rf++) {
        const int row = rf * 16 + l15;
        const int slot = ks * 4 + hi;
        av[rf] = *reinterpret_cast<const short8*>(
            act + row * 256 + ((slot ^ (row & 7)) << 3));
      }
      #pragma unroll
      for (int rf = 0; rf < 2; rf++)
        a4[rf] = __builtin_amdgcn_mfma_f32_16x16x32_bf16(av[rf], bv, a4[rf], 0, 0, 0);
    }
    if (l15 < Oo) {
      const float bs = b4[l15];
      #pragma unroll
      for (int rf = 0; rf < 2; rf++)
        #pragma unroll
        for (int rg = 0; rg < 4; rg++) {
          const int row = r0 + rf * 16 + hi * 4 + rg;
          out[(size_t)row * Oo + l15] = a4[rf][rg] + bs;
        }
    }
  }
}

// ---------------------------------------------------------------------------
extern "C" void kernel_launch(void* const* d_in, const int* in_sizes, int n_in,
                              void* d_out, int out_size, void* d_ws, size_t ws_size,
                              hipStream_t stream)
{
  const float* x     = (const float*)d_in[0];
  const int*   ei    = (const int*)d_in[1];
  const float* ea    = (const float*)d_in[2];
  const int*   batch = (const int*)d_in[3];
  const int* src = ei;
  const int* dst = ei + Ee;

  const float *We[3], *be_[3], *W1[3], *b1[3], *g_[3], *bt_[3], *mu_[3], *var_[3], *W2[3], *b2[3];
  for (int l = 0; l < 3; l++) {
    const int base = 4 + l * 10;
    We[l]  = (const float*)d_in[base + 0];
    be_[l] = (const float*)d_in[base + 1];
    W1[l]  = (const float*)d_in[base + 2];
    b1[l]  = (const float*)d_in[base + 3];
    g_[l]  = (const float*)d_in[base + 4];
    bt_[l] = (const float*)d_in[base + 5];
    mu_[l] = (const float*)d_in[base + 6];
    var_[l]= (const float*)d_in[base + 7];
    W2[l]  = (const float*)d_in[base + 8];
    b2[l]  = (const float*)d_in[base + 9];
  }
  const float *Wm[4], *bm[4];
  for (int i = 0; i < 4; i++) {
    Wm[i] = (const float*)d_in[34 + 2 * i];
    bm[i] = (const float*)d_in[35 + 2 * i];
  }

  // ---- workspace layout ----
  int* deg     = (int*)d_ws;                        // Nn
  int* cursor  = deg + Nn;                          // Nn
  int* row_ptr = cursor + Nn;                       // Nn+4
  int* bsum    = row_ptr + Nn + 4;                  // 64
  int* boff    = bsum + 64;                         // 64
  int* csr_src = boff + 64;                         // Ee
  float* eaP   = (float*)(csr_src + Ee);            // 3*Ee
  unsigned short* x0bf = (unsigned short*)(eaP + (size_t)3 * Ee);  // Nn*128
  unsigned short* Wt11 = x0bf + (size_t)Nn * 128;   // 256x128
  unsigned short* Wt12 = Wt11 + 32768;              // 256x256 each
  unsigned short* Wt21 = Wt12 + 65536;
  unsigned short* Wt22 = Wt21 + 65536;
  unsigned short* Wt31 = Wt22 + 65536;
  unsigned short* Wt32 = Wt31 + 65536;
  unsigned short* HW1t = Wt32 + 65536;              // 256x768
  unsigned short* HW2t = HW1t + 256 * 768;          // 256x256
  unsigned short* HW3t = HW2t + 65536;
  unsigned short* HW4t = HW3t + 65536;
  unsigned short* S    = HW4t + 65536;              // Nn*256
  unsigned short* Y    = S  + (size_t)Nn * Hh;      // Nn*256
  unsigned short* XB0  = Y  + (size_t)Nn * Hh;      // Nn*256
  unsigned short* XB1  = XB0 + (size_t)Nn * Hh;     // Nn*256
  unsigned short* Pbf  = XB1 + (size_t)Nn * Hh;     // Gg*768
  float* pooled = (float*)(Pbf + (size_t)Gg * 768); // Gg*768
  float* outf  = (float*)d_out;

  const dim3 gemmGrid(2, (Nn + 127) / 128);
  const int  poolGrid = (Nn + 15) / 16;
  const int  aggGrid  = (Nn + 3) / 4;
  const int  eGrid    = (Ee + 255) / 256;
  const int  sGrid    = (Nn + 1023) / 1024;

  hipMemsetAsync(deg, 0, Nn * sizeof(int), stream);
  hipMemsetAsync(pooled, 0, (size_t)Gg * 768 * sizeof(float), stream);

  // CSR build (once)
  hist_kernel<<<eGrid, 256, 0, stream>>>(dst, deg);
  scan1_kernel<<<sGrid, 1024, 0, stream>>>(deg, bsum);
  scan2_kernel<<<1, 64, 0, stream>>>(bsum, boff, row_ptr, sGrid);
  scan3_kernel<<<sGrid, 1024, 0, stream>>>(deg, boff, row_ptr, cursor);
  fill_kernel<<<eGrid, 256, 0, stream>>>(src, dst, ea, cursor, csr_src, eaP);

  // converts
  f2bf_kernel<<<(Nn * 128 / 4 + 255) / 256, 256, 0, stream>>>(x, x0bf, Nn * 128 / 4);
  wt_kernel<<<(256 * 128 + 255) / 256, 256, 0, stream>>>(W1[0], Wt11, 128);
  wt_kernel<<<(256 * 256 + 255) / 256, 256, 0, stream>>>(W2[0], Wt12, 256);
  wt_kernel<<<(256 * 256 + 255) / 256, 256, 0, stream>>>(W1[1], Wt21, 256);
  wt_kernel<<<(256 * 256 + 255) / 256, 256, 0, stream>>>(W2[1], Wt22, 256);
  wt_kernel<<<(256 * 256 + 255) / 256, 256, 0, stream>>>(W1[2], Wt31, 256);
  wt_kernel<<<(256 * 256 + 255) / 256, 256, 0, stream>>>(W2[2], Wt32, 256);
  headwt_kernel<<<(256 * 768 + 255) / 256, 256, 0, stream>>>(Wm[0], HW1t, 768, 200, 768);
  headwt_kernel<<<(256 * 256 + 255) / 256, 256, 0, stream>>>(Wm[1], HW2t, 200, 200, 256);
  headwt_kernel<<<(256 * 256 + 255) / 256, 256, 0, stream>>>(Wm[2], HW3t, 200, 200, 256);
  headwt_kernel<<<(256 * 256 + 255) / 256, 256, 0, stream>>>(Wm[3], HW4t, 200, 10, 256);

  // ---- layer 1 (din = 128) ----
  agg_gather<128><<<aggGrid, 256, 0, stream>>>(x0bf, eaP, We[0], be_[0], row_ptr, csr_src, S);
  gemm_mfma<128, true><<<gemmGrid, 256, 0, stream>>>(
      S, Wt11, b1[0], g_[0], bt_[0], mu_[0], var_[0], Y);
  gemm_mfma<256, false><<<gemmGrid, 256, 0, stream>>>(
      Y, Wt12, b2[0], nullptr, nullptr, nullptr, nullptr, XB0);
  pool_kernel<<<poolGrid, 256, 0, stream>>>(XB0, batch, pooled, 0);

  // ---- layer 2 (din = 256) ----
  agg_gather<256><<<aggGrid, 256, 0, stream>>>(XB0, eaP, We[1], be_[1], row_ptr, csr_src, S);
  gemm_mfma<256, true><<<gemmGrid, 256, 0, stream>>>(
      S, Wt21, b1[1], g_[1], bt_[1], mu_[1], var_[1], Y);
  gemm_mfma<256, false><<<gemmGrid, 256, 0, stream>>>(
      Y, Wt22, b2[1], nullptr, nullptr, nullptr, nullptr, XB1);
  pool_kernel<<<poolGrid, 256, 0, stream>>>(XB1, batch, pooled, 1);

  // ---- layer 3 (din = 256) ----
  agg_gather<256><<<aggGrid, 256, 0, stream>>>(XB1, eaP, We[2], be_[2], row_ptr, csr_src, S);
  gemm_mfma<256, true><<<gemmGrid, 256, 0, stream>>>(
      S, Wt31, b1[2], g_[2], bt_[2], mu_[2], var_[2], Y);
  gemm_mfma<256, false><<<gemmGrid, 256, 0, stream>>>(
      Y, Wt32, b2[2], nullptr, nullptr, nullptr, nullptr, XB0);
  pool_kernel<<<poolGrid, 256, 0, stream>>>(XB0, batch, pooled, 2);

  // ---- fused MFMA head ----
  f2bf_kernel<<<(Gg * 768 / 4 + 255) / 256, 256, 0, stream>>>(pooled, Pbf, Gg * 768 / 4);
  head_fused<<<4, 256, 0, stream>>>(Pbf, HW1t, HW2t, HW3t, HW4t,
                                    bm[0], bm[1], bm[2], bm[3], outf);
}

// Round 7
// 712.017 us; speedup vs baseline: 1.6022x; 1.0234x over previous
//
#include <hip/hip_runtime.h>

#define LRELU(v) ((v) >= 0.f ? (v) : 0.2f * (v))
#define DLRELU(v) ((v) >= 0.f ? (v) : 0.04f * (v))

constexpr int Nn = 50000;
constexpr int Ee = 800000;
constexpr int Hh = 256;
constexpr int Gg = 128;
constexpr int Oo = 10;

typedef __attribute__((ext_vector_type(8))) short short8;
typedef __attribute__((ext_vector_type(4))) float f32x4;
typedef __attribute__((ext_vector_type(4))) float fv4;
typedef __attribute__((ext_vector_type(4))) unsigned short us4;

__device__ inline float bf2f(unsigned short u) {
  union { unsigned int i; float f; } v; v.i = ((unsigned int)u) << 16; return v.f;
}
__device__ inline unsigned short f2bf(float f) {
  union { float f; unsigned int i; } v; v.f = f;
  unsigned int i = v.i;
  return (unsigned short)((i + 0x7FFFu + ((i >> 16) & 1u)) >> 16);
}

typedef __attribute__((address_space(1))) const unsigned int gu32;
typedef __attribute__((address_space(3))) unsigned int lu32;
__device__ inline void gload_lds16(const void* g, void* l) {
  __builtin_amdgcn_global_load_lds((gu32*)g, (lu32*)l, 16, 0, 0);
}

// ---------------------------------------------------------------------------
// CSR build
// ---------------------------------------------------------------------------
__global__ __launch_bounds__(256) void hist_kernel(
    const int* __restrict__ dst, int* __restrict__ deg)
{
  const int e = blockIdx.x * 256 + threadIdx.x;
  if (e < Ee) atomicAdd(&deg[dst[e]], 1);
}

__global__ __launch_bounds__(1024) void scan1_kernel(
    const int* __restrict__ deg, int* __restrict__ bsum)
{
  const int i = blockIdx.x * 1024 + threadIdx.x;
  int v = (i < Nn) ? deg[i] : 0;
  #pragma unroll
  for (int o = 32; o; o >>= 1) v += __shfl_xor(v, o, 64);
  __shared__ int ws[16];
  const int wid = threadIdx.x >> 6, lane = threadIdx.x & 63;
  if (lane == 0) ws[wid] = v;
  __syncthreads();
  if (threadIdx.x == 0) {
    int s = 0;
    #pragma unroll
    for (int k = 0; k < 16; k++) s += ws[k];
    bsum[blockIdx.x] = s;
  }
}

__global__ __launch_bounds__(64) void scan2_kernel(
    const int* __restrict__ bsum, int* __restrict__ boff, int* __restrict__ row_ptr, int nb)
{
  if (threadIdx.x == 0) {
    int s = 0;
    for (int b = 0; b < nb; b++) { boff[b] = s; s += bsum[b]; }
    row_ptr[Nn] = s;
  }
}

__global__ __launch_bounds__(1024) void scan3_kernel(
    const int* __restrict__ deg, const int* __restrict__ boff,
    int* __restrict__ row_ptr, int* __restrict__ cursor)
{
  const int i = blockIdx.x * 1024 + threadIdx.x;
  const int wid = threadIdx.x >> 6, lane = threadIdx.x & 63;
  const int v = (i < Nn) ? deg[i] : 0;
  int inc = v;
  #pragma unroll
  for (int o = 1; o < 64; o <<= 1) {
    const int u = __shfl_up(inc, o, 64);
    if (lane >= o) inc += u;
  }
  __shared__ int ws[16];
  if (lane == 63) ws[wid] = inc;
  __syncthreads();
  if (wid == 0 && lane < 16) {
    int s = ws[lane];
    #pragma unroll
    for (int o = 1; o < 16; o <<= 1) {
      const int u = __shfl_up(s, o, 64);
      if (lane >= o) s += u;
    }
    ws[lane] = s;
  }
  __syncthreads();
  const int woff = (wid == 0) ? 0 : ws[wid - 1];
  const int excl = boff[blockIdx.x] + woff + inc - v;
  if (i < Nn) { row_ptr[i] = excl; cursor[i] = excl; }
}

// fill: packed 16B edge record {src, a0, a1, a2} in CSR order
__global__ __launch_bounds__(256) void fill_kernel(
    const int* __restrict__ src, const int* __restrict__ dst,
    const float* __restrict__ ea, int* __restrict__ cursor,
    fv4* __restrict__ edges)
{
  const int e = blockIdx.x * 256 + threadIdx.x;
  if (e >= Ee) return;
  const int pos = atomicAdd(&cursor[dst[e]], 1);
  fv4 r;
  r.x = __int_as_float(src[e]);
  r.y = ea[3 * e + 0];
  r.z = ea[3 * e + 1];
  r.w = ea[3 * e + 2];
  edges[pos] = r;
}

// ---------------------------------------------------------------------------
// Converters
// ---------------------------------------------------------------------------
__global__ __launch_bounds__(256) void f2bf_kernel(
    const float* __restrict__ in, unsigned short* __restrict__ out, int n4)
{
  const int i = blockIdx.x * 256 + threadIdx.x;
  if (i >= n4) return;
  const float4 v = *reinterpret_cast<const float4*>(in + (size_t)i * 4);
  us4 o; o.x = f2bf(v.x); o.y = f2bf(v.y); o.z = f2bf(v.z); o.w = f2bf(v.w);
  *reinterpret_cast<us4*>(out + (size_t)i * 4) = o;
}

// W [K,256] fp32 -> Bt [256,K] bf16 (transpose+convert)
__global__ __launch_bounds__(256) void wt_kernel(
    const float* __restrict__ W, unsigned short* __restrict__ Bt, int K)
{
  const int g = blockIdx.x * 256 + threadIdx.x;
  if (g >= 256 * K) return;
  const int c = g & 255, k = g >> 8;
  Bt[(size_t)c * K + k] = f2bf(W[(size_t)k * 256 + c]);
}

// head weights: W[K,M] fp32 -> Bt[256,Kpad] bf16 transposed, zero-padded
__global__ __launch_bounds__(256) void headwt_kernel(
    const float* __restrict__ W, unsigned short* __restrict__ Bt,
    int K, int M, int Kpad)
{
  const int g = blockIdx.x * 256 + threadIdx.x;
  if (g >= 256 * Kpad) return;
  const int c = g / Kpad, k = g % Kpad;
  Bt[(size_t)c * Kpad + k] = (c < M && k < K) ? f2bf(W[(size_t)k * M + c]) : (unsigned short)0;
}

// ---------------------------------------------------------------------------
// Gather aggregation v2: packed edges, unroll-2, 32-bit addressing, NT streams
// S[n] = bf16( x[n] + sum_e ReLU(x[src_e] + ea_e@We + be) )
// ---------------------------------------------------------------------------
template<int DIN>
__global__ __launch_bounds__(256) void agg_gather(
    const unsigned short* __restrict__ x, const fv4* __restrict__ edges,
    const float* __restrict__ We, const float* __restrict__ be,
    const int* __restrict__ row_ptr, unsigned short* __restrict__ S)
{
  constexpr int FPL = DIN / 64;
  constexpr int SH = (DIN == 256) ? 8 : 7;
  const int wv   = threadIdx.x >> 6;
  const int lane = threadIdx.x & 63;
  const int n = blockIdx.x * 4 + wv;
  if (n >= Nn) return;
  const int fo = lane * FPL;

  float w0[FPL], w1[FPL], w2[FPL], bb[FPL], acc[FPL];
  #pragma unroll
  for (int j = 0; j < FPL; j++) {
    w0[j] = We[0 * DIN + fo + j];
    w1[j] = We[1 * DIN + fo + j];
    w2[j] = We[2 * DIN + fo + j];
    bb[j] = be[fo + j];
    acc[j] = 0.f;
  }

  const int beg = row_ptr[n], end = row_ptr[n + 1];
  int i = beg;
  for (; i + 2 <= end; i += 2) {
    const fv4 e0 = __builtin_nontemporal_load(edges + i);
    const fv4 e1 = __builtin_nontemporal_load(edges + i + 1);
    const unsigned o0 = ((unsigned)__float_as_int(e0.x) << SH) + fo;
    const unsigned o1 = ((unsigned)__float_as_int(e1.x) << SH) + fo;
    float xv0[FPL], xv1[FPL];
    if constexpr (FPL == 4) {
      const us4 v0 = *reinterpret_cast<const us4*>(x + o0);
      const us4 v1 = *reinterpret_cast<const us4*>(x + o1);
      xv0[0] = bf2f(v0.x); xv0[1] = bf2f(v0.y); xv0[2] = bf2f(v0.z); xv0[3] = bf2f(v0.w);
      xv1[0] = bf2f(v1.x); xv1[1] = bf2f(v1.y); xv1[2] = bf2f(v1.z); xv1[3] = bf2f(v1.w);
    } else {
      const unsigned int u0 = *reinterpret_cast<const unsigned int*>(x + o0);
      const unsigned int u1 = *reinterpret_cast<const unsigned int*>(x + o1);
      xv0[0] = bf2f((unsigned short)(u0 & 0xFFFF)); xv0[1] = bf2f((unsigned short)(u0 >> 16));
      xv1[0] = bf2f((unsigned short)(u1 & 0xFFFF)); xv1[1] = bf2f((unsigned short)(u1 >> 16));
    }
    #pragma unroll
    for (int j = 0; j < FPL; j++) {
      acc[j] += fmaxf(xv0[j] + e0.y * w0[j] + e0.z * w1[j] + e0.w * w2[j] + bb[j], 0.f);
      acc[j] += fmaxf(xv1[j] + e1.y * w0[j] + e1.z * w1[j] + e1.w * w2[j] + bb[j], 0.f);
    }
  }
  if (i < end) {
    const fv4 e0 = __builtin_nontemporal_load(edges + i);
    const unsigned o0 = ((unsigned)__float_as_int(e0.x) << SH) + fo;
    float xv0[FPL];
    if constexpr (FPL == 4) {
      const us4 v0 = *reinterpret_cast<const us4*>(x + o0);
      xv0[0] = bf2f(v0.x); xv0[1] = bf2f(v0.y); xv0[2] = bf2f(v0.z); xv0[3] = bf2f(v0.w);
    } else {
      const unsigned int u0 = *reinterpret_cast<const unsigned int*>(x + o0);
      xv0[0] = bf2f((unsigned short)(u0 & 0xFFFF)); xv0[1] = bf2f((unsigned short)(u0 >> 16));
    }
    #pragma unroll
    for (int j = 0; j < FPL; j++)
      acc[j] += fmaxf(xv0[j] + e0.y * w0[j] + e0.z * w1[j] + e0.w * w2[j] + bb[j], 0.f);
  }

  // add own node features and emit bf16 (non-temporal: S streams, protect x in L2)
  const unsigned on = ((unsigned)n << SH) + fo;
  if constexpr (FPL == 4) {
    const us4 v = *reinterpret_cast<const us4*>(x + on);
    us4 ov;
    ov.x = f2bf(bf2f(v.x) + acc[0]); ov.y = f2bf(bf2f(v.y) + acc[1]);
    ov.z = f2bf(bf2f(v.z) + acc[2]); ov.w = f2bf(bf2f(v.w) + acc[3]);
    __builtin_nontemporal_store(ov, reinterpret_cast<us4*>(S + on));
  } else {
    const unsigned int u = *reinterpret_cast<const unsigned int*>(x + on);
    const unsigned short o0 = f2bf(bf2f((unsigned short)(u & 0xFFFF)) + acc[0]);
    const unsigned short o1 = f2bf(bf2f((unsigned short)(u >> 16)) + acc[1]);
    __builtin_nontemporal_store((unsigned int)o0 | ((unsigned int)o1 << 16),
                                reinterpret_cast<unsigned int*>(S + on));
  }
}

// ---------------------------------------------------------------------------
// MFMA GEMM (m97-style): C[N,256] = epi( A[N,K]bf16 @ W[K,256] ), Bt=W^T [256][K]
// 128x128 block tile, 4 waves (2x2, 64x64 each), BK=64, gload_lds + XOR swizzle
// ---------------------------------------------------------------------------
template<int K, bool DOBN>
__global__ __launch_bounds__(256) void gemm_mfma(
    const unsigned short* __restrict__ A, const unsigned short* __restrict__ Bt,
    const float* __restrict__ bias,
    const float* __restrict__ gamma, const float* __restrict__ beta,
    const float* __restrict__ mu, const float* __restrict__ var,
    unsigned short* __restrict__ C)
{
  __shared__ __align__(16) unsigned short lA[128 * 64];
  __shared__ __align__(16) unsigned short lB[128 * 64];
  const int t = threadIdx.x;
  const int lane = t & 63, wid = t >> 6;
  const int wrow = wid >> 1, wcol = wid & 1;
  const int l15 = lane & 15, hi = lane >> 4;
  const int n0 = blockIdx.y * 128;
  const int c0 = blockIdx.x * 128;
  const int srow = lane >> 3;
  const int sslot = lane & 7;

  f32x4 acc[4][4] = {};

  for (int k0 = 0; k0 < K; k0 += 64) {
    #pragma unroll
    for (int c = 0; c < 4; c++) {
      const int chunk = wid * 4 + c;
      const int row = chunk * 8 + srow;
      const int scol = (sslot ^ (row & 7)) * 8;
      const int gr = min(n0 + row, Nn - 1);
      gload_lds16(A + (size_t)gr * K + k0 + scol, (char*)lA + chunk * 1024);
      const int cb = c0 + row;
      gload_lds16(Bt + (size_t)cb * K + k0 + scol, (char*)lB + chunk * 1024);
    }
    __syncthreads();
    #pragma unroll
    for (int kk = 0; kk < 2; kk++) {
      short8 av[4], bv[4];
      #pragma unroll
      for (int rf = 0; rf < 4; rf++) {
        const int ar = wrow * 64 + rf * 16 + l15;
        av[rf] = *reinterpret_cast<const short8*>(
            (const char*)lA + ar * 128 + (((kk * 4 + hi) ^ (ar & 7)) << 4));
      }
      #pragma unroll
      for (int cf = 0; cf < 4; cf++) {
        const int br = wcol * 64 + cf * 16 + l15;
        bv[cf] = *reinterpret_cast<const short8*>(
            (const char*)lB + br * 128 + (((kk * 4 + hi) ^ (br & 7)) << 4));
      }
      #pragma unroll
      for (int rf = 0; rf < 4; rf++)
        #pragma unroll
        for (int cf = 0; cf < 4; cf++)
          acc[rf][cf] = __builtin_amdgcn_mfma_f32_16x16x32_bf16(av[rf], bv[cf], acc[rf][cf], 0, 0, 0);
    }
    __syncthreads();
  }

  #pragma unroll
  for (int cf = 0; cf < 4; cf++) {
    const int col = c0 + wcol * 64 + cf * 16 + l15;
    const float bs = bias[col];
    float gm = 0.f, bt2 = 0.f, mm = 0.f, iv = 0.f;
    if constexpr (DOBN) {
      gm = gamma[col]; bt2 = beta[col]; mm = mu[col];
      iv = rsqrtf(var[col] + 1e-5f);
    }
    #pragma unroll
    for (int rf = 0; rf < 4; rf++) {
      #pragma unroll
      for (int rg = 0; rg < 4; rg++) {
        const int row = n0 + wrow * 64 + rf * 16 + hi * 4 + rg;
        if (row >= Nn) continue;
        float v = acc[rf][cf][rg] + bs;
        if constexpr (DOBN) v = gm * (v - mm) * iv + bt2;
        v = LRELU(v);
        C[(size_t)row * 256 + col] = f2bf(v);
      }
    }
  }
}

// ---------------------------------------------------------------------------
// Pool: segment_sum (sorted batch) of bf16 features into pooled[G,768] fp32
// ---------------------------------------------------------------------------
__global__ __launch_bounds__(256) void pool_kernel(
    const unsigned short* __restrict__ xl, const int* __restrict__ batch,
    float* __restrict__ pooled, int layer)
{
  constexpr int NPB = 16;
  const int n0 = blockIdx.x * NPB;
  const int c  = threadIdx.x;
  if (n0 >= Nn) return;
  float acc = 0.f;
  int curb = batch[n0];
  for (int i = 0; i < NPB; i++) {
    const int n = n0 + i;
    if (n >= Nn) break;
    const int b = batch[n];
    if (b != curb) {
      atomicAdd(pooled + (size_t)curb * 768 + layer * 256 + c, acc);
      acc = 0.f;
      curb = b;
    }
    acc += bf2f(xl[(size_t)n * 256 + c]);
  }
  atomicAdd(pooled + (size_t)curb * 768 + layer * 256 + c, acc);
}

// ---------------------------------------------------------------------------
// Fused MFMA head: 4 blocks x 32 graphs, all 4 layers, act in swizzled LDS
// ---------------------------------------------------------------------------
__global__ __launch_bounds__(256) void head_fused(
    const unsigned short* __restrict__ P,   // [128][768] bf16
    const unsigned short* __restrict__ B1t, // [256][768] bf16 (zero-padded)
    const unsigned short* __restrict__ B2t, // [256][256]
    const unsigned short* __restrict__ B3t, // [256][256]
    const unsigned short* __restrict__ B4t, // [256][256] (rows 0..9 real)
    const float* __restrict__ b1, const float* __restrict__ b2,
    const float* __restrict__ b3, const float* __restrict__ b4,
    float* __restrict__ out)                // [128][10]
{
  __shared__ __align__(16) unsigned short act[32 * 256];  // 16 KB, swizzled
  const int t = threadIdx.x, lane = t & 63, wid = t >> 6;
  const int l15 = lane & 15, hi = lane >> 4;
  const int r0 = blockIdx.x * 32;

  f32x4 acc[2][4];

  // ---------- layer 1: P[32][768] @ B1 -> act ----------
  #pragma unroll
  for (int rf = 0; rf < 2; rf++)
    #pragma unroll
    for (int cf = 0; cf < 4; cf++) acc[rf][cf] = (f32x4){0.f, 0.f, 0.f, 0.f};
  #pragma unroll 2
  for (int ks = 0; ks < 24; ks++) {
    short8 bv[4], av[2];
    #pragma unroll
    for (int cf = 0; cf < 4; cf++) {
      const int c = wid * 64 + cf * 16 + l15;
      bv[cf] = *reinterpret_cast<const short8*>(B1t + (size_t)c * 768 + ks * 32 + hi * 8);
    }
    #pragma unroll
    for (int rf = 0; rf < 2; rf++)
      av[rf] = *reinterpret_cast<const short8*>(
          P + (size_t)(r0 + rf * 16 + l15) * 768 + ks * 32 + hi * 8);
    #pragma unroll
    for (int rf = 0; rf < 2; rf++)
      #pragma unroll
      for (int cf = 0; cf < 4; cf++)
        acc[rf][cf] = __builtin_amdgcn_mfma_f32_16x16x32_bf16(av[rf], bv[cf], acc[rf][cf], 0, 0, 0);
  }
  #pragma unroll
  for (int cf = 0; cf < 4; cf++) {
    const int c = wid * 64 + cf * 16 + l15;
    const float bs = (c < 200) ? b1[c] : 0.f;
    const int slot0 = c >> 3;
    #pragma unroll
    for (int rf = 0; rf < 2; rf++)
      #pragma unroll
      for (int rg = 0; rg < 4; rg++) {
        const int row = rf * 16 + hi * 4 + rg;
        const float v = DLRELU(acc[rf][cf][rg] + bs);
        act[row * 256 + ((slot0 ^ (row & 7)) << 3) + (c & 7)] = f2bf(v);
      }
  }
  __syncthreads();

  // ---------- layers 2 & 3: act @ B -> act ----------
  #pragma unroll
  for (int L = 0; L < 2; L++) {
    const unsigned short* B = (L == 0) ? B2t : B3t;
    const float* bias = (L == 0) ? b2 : b3;
    #pragma unroll
    for (int rf = 0; rf < 2; rf++)
      #pragma unroll
      for (int cf = 0; cf < 4; cf++) acc[rf][cf] = (f32x4){0.f, 0.f, 0.f, 0.f};
    #pragma unroll
    for (int ks = 0; ks < 8; ks++) {
      short8 bv[4], av[2];
      #pragma unroll
      for (int cf = 0; cf < 4; cf++) {
        const int c = wid * 64 + cf * 16 + l15;
        bv[cf] = *reinterpret_cast<const short8*>(B + (size_t)c * 256 + ks * 32 + hi * 8);
      }
      #pragma unroll
      for (int rf = 0; rf < 2; rf++) {
        const int row = rf * 16 + l15;
        const int slot = ks * 4 + hi;
        av[rf] = *reinterpret_cast<const short8*>(
            act + row * 256 + ((slot ^ (row & 7)) << 3));
      }
      #pragma unroll
      for (int rf = 0; rf < 2; rf++)
        #pragma unroll
        for (int cf = 0; cf < 4; cf++)
          acc[rf][cf] = __builtin_amdgcn_mfma_f32_16x16x32_bf16(av[rf], bv[cf], acc[rf][cf], 0, 0, 0);
    }
    __syncthreads();
    #pragma unroll
    for (int cf = 0; cf < 4; cf++) {
      const int c = wid * 64 + cf * 16 + l15;
      const float bs = (c < 200) ? bias[c] : 0.f;
      const int slot0 = c >> 3;
      #pragma unroll
      for (int rf = 0; rf < 2; rf++)
        #pragma unroll
        for (int rg = 0; rg < 4; rg++) {
          const int row = rf * 16 + hi * 4 + rg;
          const float v = DLRELU(acc[rf][cf][rg] + bs);
          act[row * 256 + ((slot0 ^ (row & 7)) << 3) + (c & 7)] = f2bf(v);
        }
    }
    __syncthreads();
  }

  // ---------- layer 4: act @ B4 -> out (wave 0 only, cols 0..9) ----------
  if (wid == 0) {
    f32x4 a4[2] = {};
    #pragma unroll
    for (int ks = 0; ks < 8; ks++) {
      short8 av[2];
      const short8 bv = *reinterpret_cast<const short8*>(
          B4t + (size_t)l15 * 256 + ks * 32 + hi * 8);
      #pragma unroll
      for (int rf = 0; rf < 2; rf++) {
        const int row = rf * 16 + l15;
        const int slot = ks * 4 + hi;
        av[rf] = *reinterpret_cast<const short8*>(
            act + row * 256 + ((slot ^ (row & 7)) << 3));
      }
      #pragma unroll
      for (int rf = 0; rf < 2; rf++)
        a4[rf] = __builtin_amdgcn_mfma_f32_16x16x32_bf16(av[rf], bv, a4[rf], 0, 0, 0);
    }
    if (l15 < Oo) {
      const float bs = b4[l15];
      #pragma unroll
      for (int rf = 0; rf < 2; rf++)
        #pragma unroll
        for (int rg = 0; rg < 4; rg++) {
          const int row = r0 + rf * 16 + hi * 4 + rg;
          out[(size_t)row * Oo + l15] = a4[rf][rg] + bs;
        }
    }
  }
}

// ---------------------------------------------------------------------------
extern "C" void kernel_launch(void* const* d_in, const int* in_sizes, int n_in,
                              void* d_out, int out_size, void* d_ws, size_t ws_size,
                              hipStream_t stream)
{
  const float* x     = (const float*)d_in[0];
  const int*   ei    = (const int*)d_in[1];
  const float* ea    = (const float*)d_in[2];
  const int*   batch = (const int*)d_in[3];
  const int* src = ei;
  const int* dst = ei + Ee;

  const float *We[3], *be_[3], *W1[3], *b1[3], *g_[3], *bt_[3], *mu_[3], *var_[3], *W2[3], *b2[3];
  for (int l = 0; l < 3; l++) {
    const int base = 4 + l * 10;
    We[l]  = (const float*)d_in[base + 0];
    be_[l] = (const float*)d_in[base + 1];
    W1[l]  = (const float*)d_in[base + 2];
    b1[l]  = (const float*)d_in[base + 3];
    g_[l]  = (const float*)d_in[base + 4];
    bt_[l] = (const float*)d_in[base + 5];
    mu_[l] = (const float*)d_in[base + 6];
    var_[l]= (const float*)d_in[base + 7];
    W2[l]  = (const float*)d_in[base + 8];
    b2[l]  = (const float*)d_in[base + 9];
  }
  const float *Wm[4], *bm[4];
  for (int i = 0; i < 4; i++) {
    Wm[i] = (const float*)d_in[34 + 2 * i];
    bm[i] = (const float*)d_in[35 + 2 * i];
  }

  // ---- workspace layout ----
  int* deg     = (int*)d_ws;                        // [0, 50000)
  int* cursor  = deg + Nn;                          // [50000, 100000)
  int* row_ptr = cursor + Nn;                       // [100000, 150004)
  int* bsum    = row_ptr + Nn + 4;                  // [150004, 150068)
  int* boff    = bsum + 64;                         // [150068, 150132)
  fv4* edges   = (fv4*)(boff + 64 + 27);            // 16B-aligned; Ee*16B
  unsigned short* x0bf = (unsigned short*)(edges + Ee);  // Nn*128
  unsigned short* Wt11 = x0bf + (size_t)Nn * 128;   // 256x128
  unsigned short* Wt12 = Wt11 + 32768;              // 256x256 each
  unsigned short* Wt21 = Wt12 + 65536;
  unsigned short* Wt22 = Wt21 + 65536;
  unsigned short* Wt31 = Wt22 + 65536;
  unsigned short* Wt32 = Wt31 + 65536;
  unsigned short* HW1t = Wt32 + 65536;              // 256x768
  unsigned short* HW2t = HW1t + 256 * 768;          // 256x256
  unsigned short* HW3t = HW2t + 65536;
  unsigned short* HW4t = HW3t + 65536;
  unsigned short* S    = HW4t + 65536;              // Nn*256
  unsigned short* Y    = S  + (size_t)Nn * Hh;      // Nn*256
  unsigned short* XB0  = Y  + (size_t)Nn * Hh;      // Nn*256
  unsigned short* XB1  = XB0 + (size_t)Nn * Hh;     // Nn*256
  unsigned short* Pbf  = XB1 + (size_t)Nn * Hh;     // Gg*768
  float* pooled = (float*)(Pbf + (size_t)Gg * 768); // Gg*768
  float* outf  = (float*)d_out;

  const dim3 gemmGrid(2, (Nn + 127) / 128);
  const int  poolGrid = (Nn + 15) / 16;
  const int  aggGrid  = (Nn + 3) / 4;
  const int  eGrid    = (Ee + 255) / 256;
  const int  sGrid    = (Nn + 1023) / 1024;

  hipMemsetAsync(deg, 0, Nn * sizeof(int), stream);
  hipMemsetAsync(pooled, 0, (size_t)Gg * 768 * sizeof(float), stream);

  // CSR build (once)
  hist_kernel<<<eGrid, 256, 0, stream>>>(dst, deg);
  scan1_kernel<<<sGrid, 1024, 0, stream>>>(deg, bsum);
  scan2_kernel<<<1, 64, 0, stream>>>(bsum, boff, row_ptr, sGrid);
  scan3_kernel<<<sGrid, 1024, 0, stream>>>(deg, boff, row_ptr, cursor);
  fill_kernel<<<eGrid, 256, 0, stream>>>(src, dst, ea, cursor, edges);

  // converts
  f2bf_kernel<<<(Nn * 128 / 4 + 255) / 256, 256, 0, stream>>>(x, x0bf, Nn * 128 / 4);
  wt_kernel<<<(256 * 128 + 255) / 256, 256, 0, stream>>>(W1[0], Wt11, 128);
  wt_kernel<<<(256 * 256 + 255) / 256, 256, 0, stream>>>(W2[0], Wt12, 256);
  wt_kernel<<<(256 * 256 + 255) / 256, 256, 0, stream>>>(W1[1], Wt21, 256);
  wt_kernel<<<(256 * 256 + 255) / 256, 256, 0, stream>>>(W2[1], Wt22, 256);
  wt_kernel<<<(256 * 256 + 255) / 256, 256, 0, stream>>>(W1[2], Wt31, 256);
  wt_kernel<<<(256 * 256 + 255) / 256, 256, 0, stream>>>(W2[2], Wt32, 256);
  headwt_kernel<<<(256 * 768 + 255) / 256, 256, 0, stream>>>(Wm[0], HW1t, 768, 200, 768);
  headwt_kernel<<<(256 * 256 + 255) / 256, 256, 0, stream>>>(Wm[1], HW2t, 200, 200, 256);
  headwt_kernel<<<(256 * 256 + 255) / 256, 256, 0, stream>>>(Wm[2], HW3t, 200, 200, 256);
  headwt_kernel<<<(256 * 256 + 255) / 256, 256, 0, stream>>>(Wm[3], HW4t, 200, 10, 256);

  // ---- layer 1 (din = 128) ----
  agg_gather<128><<<aggGrid, 256, 0, stream>>>(x0bf, edges, We[0], be_[0], row_ptr, S);
  gemm_mfma<128, true><<<gemmGrid, 256, 0, stream>>>(
      S, Wt11, b1[0], g_[0], bt_[0], mu_[0], var_[0], Y);
  gemm_mfma<256, false><<<gemmGrid, 256, 0, stream>>>(
      Y, Wt12, b2[0], nullptr, nullptr, nullptr, nullptr, XB0);
  pool_kernel<<<poolGrid, 256, 0, stream>>>(XB0, batch, pooled, 0);

  // ---- layer 2 (din = 256) ----
  agg_gather<256><<<aggGrid, 256, 0, stream>>>(XB0, edges, We[1], be_[1], row_ptr, S);
  gemm_mfma<256, true><<<gemmGrid, 256, 0, stream>>>(
      S, Wt21, b1[1], g_[1], bt_[1], mu_[1], var_[1], Y);
  gemm_mfma<256, false><<<gemmGrid, 256, 0, stream>>>(
      Y, Wt22, b2[1], nullptr, nullptr, nullptr, nullptr, XB1);
  pool_kernel<<<poolGrid, 256, 0, stream>>>(XB1, batch, pooled, 1);

  // ---- layer 3 (din = 256) ----
  agg_gather<256><<<aggGrid, 256, 0, stream>>>(XB1, edges, We[2], be_[2], row_ptr, S);
  gemm_mfma<256, true><<<gemmGrid, 256, 0, stream>>>(
      S, Wt31, b1[2], g_[2], bt_[2], mu_[2], var_[2], Y);
  gemm_mfma<256, false><<<gemmGrid, 256, 0, stream>>>(
      Y, Wt32, b2[2], nullptr, nullptr, nullptr, nullptr, XB0);
  pool_kernel<<<poolGrid, 256, 0, stream>>>(XB0, batch, pooled, 2);

  // ---- fused MFMA head ----
  f2bf_kernel<<<(Gg * 768 / 4 + 255) / 256, 256, 0, stream>>>(pooled, Pbf, Gg * 768 / 4);
  head_fused<<<4, 256, 0, stream>>>(Pbf, HW1t, HW2t, HW3t, HW4t,
                                    bm[0], bm[1], bm[2], bm[3], outf);
}